// Round 8
// baseline (33.845 us; speedup 1.0000x reference)
//
#include <hip/hip_runtime.h>

#define NUM_SAMPLES 64
#define HIDDEN 64
#define Z_NEAR 2.0f
#define Z_FAR 6.0f
#define LOG2E 1.44269504088896f

typedef _Float16 half8 __attribute__((ext_vector_type(8)));
typedef __fp16  fp16x2 __attribute__((ext_vector_type(2)));
typedef float   float4t __attribute__((ext_vector_type(4)));

// 6-step wave64 inclusive add-scan, pure VALU (DPP), zero LDS traffic.
template<int CTRL, int RMASK>
__device__ __forceinline__ float dpp_add(float x) {
    const int m = __builtin_amdgcn_update_dpp(0, __float_as_int(x), CTRL, RMASK, 0xf, true);
    return x + __int_as_float(m);
}
__device__ __forceinline__ float wave_scan_add(float x) {
    x = dpp_add<0x111, 0xf>(x);   // row_shr:1
    x = dpp_add<0x112, 0xf>(x);   // row_shr:2
    x = dpp_add<0x114, 0xf>(x);   // row_shr:4
    x = dpp_add<0x118, 0xf>(x);   // row_shr:8
    x = dpp_add<0x142, 0xa>(x);   // row_bcast:15 -> rows 1,3
    x = dpp_add<0x143, 0xc>(x);   // row_bcast:31 -> rows 2,3
    return x;                     // lane63 = full sum
}

// 16B-slot index for C redistribution: 2-way banks max (free).
__device__ __forceinline__ int slot16(int s) { return 2*s + ((s>>2)&1); }

// wave-per-ray, lane-per-sample; layer-1 affine-in-t factorization (f16 pk);
// layer-2 via SWAPPED mfma_f32_16x16x32_f16: C'[j][sample] so lanes 0-15 get
// all 4 outputs contiguously -> 4 ds_write_b128 + 1 ds_read_b128 (was 20 ops).
// W2 fragment loaded direct from global (no LDS staging). 13 DS ops/ray total.
__global__ __launch_bounds__(256) void render_kernel(
    const float* __restrict__ cam,    // 4x4
    const float* __restrict__ u,      // R x S
    const float* __restrict__ cdirs,  // R x 3
    const float* __restrict__ W1,     // 6 x 64
    const float* __restrict__ b1,     // 64
    const float* __restrict__ W2,     // 64 x 4
    const float* __restrict__ b2,     // 4
    float* __restrict__ out)          // R x 3
{
    const int lane = threadIdx.x & 63;
    const int wid  = threadIdx.x >> 6;
    const int ray  = blockIdx.x * 4 + wid;
    const int grp  = lane >> 4;       // k-group
    const int col  = lane & 15;       // sample-in-tile / A row

    __shared__ __align__(16) __fp16 Ahsh[4][HIDDEN];
    __shared__ __align__(16) __fp16 Bhsh[4][HIDDEN];
    __shared__ __align__(16) float  tsh[4][NUM_SAMPLES];
    __shared__ __align__(16) float  cst[4][NUM_SAMPLES * 8];  // 16B slots, swizzled

    // camera 3x4 -> broadcast via readlane
    const float cl = (lane < 12) ? cam[lane] : 0.0f;
    float camv[12];
    #pragma unroll
    for (int i = 0; i < 12; ++i)
        camv[i] = __int_as_float(__builtin_amdgcn_readlane(__float_as_int(cl), i));

    // W1 rows + b1 for h = lane
    const float w10 = W1[0*HIDDEN+lane], w11 = W1[1*HIDDEN+lane], w12 = W1[2*HIDDEN+lane];
    const float w13 = W1[3*HIDDEN+lane], w14 = W1[4*HIDDEN+lane], w15 = W1[5*HIDDEN+lane];
    const float b1h = b1[lane];
    const float b20 = b2[0], b21 = b2[1], b22 = b2[2], b23 = b2[3];

    // W2 fragment direct from global: lane(grp,col<4) holds W2[32kt+8grp+j][col]
    // (used as the A-operand of the swapped MFMA; col>=4 lanes' rows are discarded)
    half8 wfrag[2] = {};
    if (col < 4) {
        const float* wp = W2 + (grp*8)*4 + col;
        union { fp16x2 h2[4]; half8 h8; } w0, w1;
        #pragma unroll
        for (int q = 0; q < 4; ++q) {
            w0.h2[q] = __builtin_amdgcn_cvt_pkrtz(wp[(q*2  )*4], wp[(q*2+1)*4]);
            w1.h2[q] = __builtin_amdgcn_cvt_pkrtz(wp[(32+q*2)*4], wp[(32+q*2+1)*4]);
        }
        wfrag[0] = w0.h8;
        wfrag[1] = w1.h8;
    }

    // u values for this lane's 4 m-tile samples: sample = 16m + col
    const float* up = u + ray*NUM_SAMPLES + col;
    const float u0 = up[0], u1 = up[16], u2 = up[32], u3 = up[48];
    // own-sample u (sample = lane = 16*grp + col)
    const float uown = (grp & 2) ? ((grp & 1) ? u3 : u2) : ((grp & 1) ? u1 : u0);

    const float cd0 = cdirs[ray*3+0], cd1 = cdirs[ray*3+1], cd2 = cdirs[ray*3+2];
    const float rd0 = fmaf(camv[0], cd0, fmaf(camv[1], cd1, camv[2]*cd2));
    const float rd1 = fmaf(camv[4], cd0, fmaf(camv[5], cd1, camv[6]*cd2));
    const float rd2 = fmaf(camv[8], cd0, fmaf(camv[9], cd1, camv[10]*cd2));
    const float o0 = camv[3], o1 = camv[7], o2 = camv[11];

    // per-hidden-unit affine coeffs: pre_h(t) = A_h*t + B_h (h = lane), staged f16
    {
        const float A = fmaf(rd0, w10, fmaf(rd1, w11, rd2*w12));
        float B = fmaf(o0, w10, fmaf(o1, w11, o2*w12));
        B = fmaf(rd0, w13, fmaf(rd1, w14, fmaf(rd2, w15, B))) + b1h;
        Ahsh[wid][lane] = (__fp16)A;
        Bhsh[wid][lane] = (__fp16)B;
    }

    const float bin_dt = (Z_FAR - Z_NEAR) / (float)NUM_SAMPLES;
    const float t = fmaf((float)lane + uown, bin_dt, Z_NEAR);
    tsh[wid][lane] = t;

    // gather fp16 coefficient pairs: h = kt*32 + grp*8 + 2q  (4 ds_read_b128)
    union { fp16x2 h2[4]; half8 h8; } aAh[2], aBh[2];
    #pragma unroll
    for (int kt = 0; kt < 2; ++kt) {
        const int h0 = kt*32 + grp*8;
        aAh[kt].h8 = *(const half8*)(&Ahsh[wid][h0]);
        aBh[kt].h8 = *(const half8*)(&Bhsh[wid][h0]);
    }

    const float tn  = tsh[wid][(lane+1) & 63];
    const float sep = (lane < NUM_SAMPLES-1) ? (tn - t) : bin_dt;

    const fp16x2 hzero = {(__fp16)0.0f, (__fp16)0.0f};

    // 4 M-tiles; swapped MFMA -> lanes 0-15 accumulate all 4 outputs of
    // sample 16m+lane in c[0..3]; single b128 write per tile.
    #pragma unroll
    for (int m = 0; m < 4; ++m) {
        const float um = (m == 0) ? u0 : (m == 1) ? u1 : (m == 2) ? u2 : u3;
        const float tm = fmaf((float)(16*m + col) + um, bin_dt, Z_NEAR);
        const fp16x2 tvh = __builtin_amdgcn_cvt_pkrtz(tm, tm);
        float4t c = {0.f, 0.f, 0.f, 0.f};
        #pragma unroll
        for (int kt = 0; kt < 2; ++kt) {
            union { fp16x2 h2[4]; half8 h8; } au;
            #pragma unroll
            for (int q = 0; q < 4; ++q) {
                const fp16x2 pre = __builtin_elementwise_fma(aAh[kt].h2[q], tvh, aBh[kt].h2[q]);
                au.h2[q] = __builtin_elementwise_max(pre, hzero);
            }
            c = __builtin_amdgcn_mfma_f32_16x16x32_f16(wfrag[kt], au.h8, c, 0, 0, 0);
        }
        if (lane < 16)
            *(float4t*)(&cst[wid][slot16(16*m + lane) * 4]) = c;
    }

    // readback: lane s gets its 4 outputs in one b128 read
    const float4t c4 = *(const float4t*)(&cst[wid][slot16(lane) * 4]);
    const float acc0 = c4[0] + b20;
    const float acc1 = c4[1] + b21;
    const float acc2 = c4[2] + b22;
    const float acc3 = c4[3] + b23;

    // composite: log2-space cumprod via DPP scan, single-inst exp2
    const float density = fmaxf(acc0, 0.0f);
    const float dsep  = density * sep;
    const float lg    = -dsep * LOG2E;                  // log2(1-alpha)
    const float alpha = 1.0f - __builtin_amdgcn_exp2f(lg);
    const float S     = wave_scan_add(lg);              // inclusive cumsum
    const float T     = __builtin_amdgcn_exp2f(S - lg); // exclusive transmittance
    const float w     = alpha * T;

    float c0 = w * __builtin_amdgcn_rcpf(1.0f + __builtin_amdgcn_exp2f(-acc1 * LOG2E));
    float c1 = w * __builtin_amdgcn_rcpf(1.0f + __builtin_amdgcn_exp2f(-acc2 * LOG2E));
    float c2 = w * __builtin_amdgcn_rcpf(1.0f + __builtin_amdgcn_exp2f(-acc3 * LOG2E));
    c0 = wave_scan_add(c0);                             // lane63 = total
    c1 = wave_scan_add(c1);
    c2 = wave_scan_add(c2);
    if (lane == 63) {
        out[ray*3+0] = c0;
        out[ray*3+1] = c1;
        out[ray*3+2] = c2;
    }
}

extern "C" void kernel_launch(void* const* d_in, const int* in_sizes, int n_in,
                              void* d_out, int out_size, void* d_ws, size_t ws_size,
                              hipStream_t stream) {
    const float* cam   = (const float*)d_in[0];
    const float* u     = (const float*)d_in[1];
    const float* cdirs = (const float*)d_in[2];
    const float* W1    = (const float*)d_in[3];
    const float* b1    = (const float*)d_in[4];
    const float* W2    = (const float*)d_in[5];
    const float* b2    = (const float*)d_in[6];
    float* out = (float*)d_out;

    const int R = 256 * 256;
    dim3 grid(R / 4), block(256);
    render_kernel<<<grid, block, 0, stream>>>(cam, u, cdirs, W1, b1, W2, b2, out);
}

// Round 9
// 28.187 us; speedup vs baseline: 1.2008x; 1.2008x over previous
//
#include <hip/hip_runtime.h>

#define NUM_SAMPLES 64
#define HIDDEN 64
#define Z_NEAR 2.0f
#define Z_FAR 6.0f
#define LOG2E 1.44269504088896f

typedef _Float16 half8 __attribute__((ext_vector_type(8)));
typedef __fp16  fp16x2 __attribute__((ext_vector_type(2)));
typedef float   float4t __attribute__((ext_vector_type(4)));

// 6-step wave64 inclusive add-scan, pure VALU (DPP), zero LDS traffic.
template<int CTRL, int RMASK>
__device__ __forceinline__ float dpp_add(float x) {
    const int m = __builtin_amdgcn_update_dpp(0, __float_as_int(x), CTRL, RMASK, 0xf, true);
    return x + __int_as_float(m);
}
__device__ __forceinline__ float wave_scan_add(float x) {
    x = dpp_add<0x111, 0xf>(x);   // row_shr:1
    x = dpp_add<0x112, 0xf>(x);   // row_shr:2
    x = dpp_add<0x114, 0xf>(x);   // row_shr:4
    x = dpp_add<0x118, 0xf>(x);   // row_shr:8
    x = dpp_add<0x142, 0xa>(x);   // row_bcast:15 -> rows 1,3
    x = dpp_add<0x143, 0xc>(x);   // row_bcast:31 -> rows 2,3
    return x;                     // lane63 = full sum
}

// 16B-slot swizzle for C redistribution: <=2-way banks (free).
__device__ __forceinline__ int slot16(int s) { return 2*s + ((s>>2)&1); }

// R6 structure (best known: 30.3us) + swapped-operand MFMA output path:
// C' = W2frag(A) x act(B) puts all 4 outputs of sample 16m+col in lanes 0-15
// -> cst becomes 4 pred ds_write_b128 + 1 ds_read_b128 (was 16+4).
// Everything else identical to R6. Per-wave LDS only -> no barriers.
__global__ __launch_bounds__(256) void render_kernel(
    const float* __restrict__ cam,    // 4x4
    const float* __restrict__ u,      // R x S
    const float* __restrict__ cdirs,  // R x 3
    const float* __restrict__ W1,     // 6 x 64
    const float* __restrict__ b1,     // 64
    const float* __restrict__ W2,     // 64 x 4
    const float* __restrict__ b2,     // 4
    float* __restrict__ out)          // R x 3
{
    const int lane = threadIdx.x & 63;
    const int wid  = threadIdx.x >> 6;
    const int ray  = blockIdx.x * 4 + wid;
    const int grp  = lane >> 4;       // k-group
    const int col  = lane & 15;       // sample-in-tile

    __shared__ __align__(16) __fp16 Ahsh[4][HIDDEN];
    __shared__ __align__(16) __fp16 Bhsh[4][HIDDEN];
    __shared__ __align__(16) float  tsh[4][NUM_SAMPLES];
    __shared__ __align__(16) __fp16 W2T[4][4][80];         // fp16 W2^T, padded rows
    __shared__ __align__(16) float  cst[4][NUM_SAMPLES*8]; // 16B slots, swizzled

    // per-wave fp16 W2^T staging (lane = hidden unit h)
    {
        const float4 w2row = ((const float4*)W2)[lane];
        W2T[wid][0][lane] = (__fp16)w2row.x;
        W2T[wid][1][lane] = (__fp16)w2row.y;
        W2T[wid][2][lane] = (__fp16)w2row.z;
        W2T[wid][3][lane] = (__fp16)w2row.w;
    }

    // ray dir / origin (cam: uniform-address scalar loads)
    const float cd0 = cdirs[ray*3+0], cd1 = cdirs[ray*3+1], cd2 = cdirs[ray*3+2];
    const float rd0 = fmaf(cam[0], cd0, fmaf(cam[1], cd1, cam[2]*cd2));
    const float rd1 = fmaf(cam[4], cd0, fmaf(cam[5], cd1, cam[6]*cd2));
    const float rd2 = fmaf(cam[8], cd0, fmaf(cam[9], cd1, cam[10]*cd2));
    const float o0 = cam[3], o1 = cam[7], o2 = cam[11];

    // per-hidden-unit affine coeffs: pre_h(t) = A_h*t + B_h (h = lane)
    {
        const int h = lane;
        const float w10 = W1[0*HIDDEN+h], w11 = W1[1*HIDDEN+h], w12 = W1[2*HIDDEN+h];
        const float w13 = W1[3*HIDDEN+h], w14 = W1[4*HIDDEN+h], w15 = W1[5*HIDDEN+h];
        const float A = fmaf(rd0, w10, fmaf(rd1, w11, rd2*w12));
        float B = fmaf(o0, w10, fmaf(o1, w11, o2*w12));
        B = fmaf(rd0, w13, fmaf(rd1, w14, fmaf(rd2, w15, B))) + b1[h];
        Ahsh[wid][lane] = (__fp16)A;
        Bhsh[wid][lane] = (__fp16)B;
    }

    const float bin_dt = (Z_FAR - Z_NEAR) / (float)NUM_SAMPLES;
    const float uv = u[ray*NUM_SAMPLES + lane];             // coalesced
    const float t  = fmaf((float)lane + uv, bin_dt, Z_NEAR);
    tsh[wid][lane] = t;

    // hoisted fp16 coefficient pairs: h = kt*32 + grp*8 + 2q
    union { fp16x2 h2[4]; half8 h8; } aAh[2], aBh[2];
    #pragma unroll
    for (int kt = 0; kt < 2; ++kt) {
        const int h0 = kt*32 + grp*8;
        aAh[kt].h8 = *(const half8*)(&Ahsh[wid][h0]);
        aBh[kt].h8 = *(const half8*)(&Bhsh[wid][h0]);
    }

    // W-fragment (A-operand of swapped MFMA): W2T rows, zero for col>=4
    half8 bfrag[2] = {};
    if (col < 4) {
        bfrag[0] = *(const half8*)(&W2T[wid][col][grp*8]);
        bfrag[1] = *(const half8*)(&W2T[wid][col][32 + grp*8]);
    }
    const float b20 = b2[0], b21 = b2[1], b22 = b2[2], b23 = b2[3];

    // sep from neighbor t (per-wave LDS, conflict-free)
    const float tn  = tsh[wid][(lane+1) & 63];
    const float sep = (lane < NUM_SAMPLES-1) ? (tn - t) : bin_dt;

    const fp16x2 hzero = {(__fp16)0.0f, (__fp16)0.0f};

    // 4 M-tiles; A-frag build (pk_fma_f16 + pk_max_f16) + 2 swapped MFMA;
    // lanes 0-15 hold outputs 0-3 of sample 16m+col -> one b128 write.
    #pragma unroll
    for (int m = 0; m < 4; ++m) {
        const float tm = tsh[wid][col + 16*m];
        const fp16x2 tvh = __builtin_amdgcn_cvt_pkrtz(tm, tm);
        float4t c = {0.f, 0.f, 0.f, 0.f};
        #pragma unroll
        for (int kt = 0; kt < 2; ++kt) {
            union { fp16x2 h2[4]; half8 h8; } au;
            #pragma unroll
            for (int q = 0; q < 4; ++q) {
                const fp16x2 pre = __builtin_elementwise_fma(aAh[kt].h2[q], tvh, aBh[kt].h2[q]);
                au.h2[q] = __builtin_elementwise_max(pre, hzero);
            }
            c = __builtin_amdgcn_mfma_f32_16x16x32_f16(bfrag[kt], au.h8, c, 0, 0, 0);
        }
        if (lane < 16)
            *(float4t*)(&cst[wid][slot16(16*m + lane) * 4]) = c;
    }

    // readback: lane s reads its 4 outputs in one b128
    const float4t c4 = *(const float4t*)(&cst[wid][slot16(lane) * 4]);
    const float acc0 = c4[0] + b20;
    const float acc1 = c4[1] + b21;
    const float acc2 = c4[2] + b22;
    const float acc3 = c4[3] + b23;

    // composite: log2-space cumprod via DPP scan, single-inst exp2
    const float density = fmaxf(acc0, 0.0f);
    const float dsep  = density * sep;
    const float lg    = -dsep * LOG2E;                  // log2(1-alpha)
    const float alpha = 1.0f - __builtin_amdgcn_exp2f(lg);
    const float S     = wave_scan_add(lg);              // inclusive cumsum
    const float T     = __builtin_amdgcn_exp2f(S - lg); // exclusive transmittance
    const float w     = alpha * T;

    float c0 = w * __builtin_amdgcn_rcpf(1.0f + __builtin_amdgcn_exp2f(-acc1 * LOG2E));
    float c1 = w * __builtin_amdgcn_rcpf(1.0f + __builtin_amdgcn_exp2f(-acc2 * LOG2E));
    float c2 = w * __builtin_amdgcn_rcpf(1.0f + __builtin_amdgcn_exp2f(-acc3 * LOG2E));
    c0 = wave_scan_add(c0);                             // lane63 = total
    c1 = wave_scan_add(c1);
    c2 = wave_scan_add(c2);
    if (lane == 63) {
        out[ray*3+0] = c0;
        out[ray*3+1] = c1;
        out[ray*3+2] = c2;
    }
}

extern "C" void kernel_launch(void* const* d_in, const int* in_sizes, int n_in,
                              void* d_out, int out_size, void* d_ws, size_t ws_size,
                              hipStream_t stream) {
    const float* cam   = (const float*)d_in[0];
    const float* u     = (const float*)d_in[1];
    const float* cdirs = (const float*)d_in[2];
    const float* W1    = (const float*)d_in[3];
    const float* b1    = (const float*)d_in[4];
    const float* W2    = (const float*)d_in[5];
    const float* b2    = (const float*)d_in[6];
    float* out = (float*)d_out;

    const int R = 256 * 256;
    dim3 grid(R / 4), block(256);
    render_kernel<<<grid, block, 0, stream>>>(cam, u, cdirs, W1, b1, W2, b2, out);
}